// Round 13
// baseline (252.912 us; speedup 1.0000x reference)
//
#include <hip/hip_runtime.h>
#include <hip/hip_fp16.h>
#include <math.h>

#define HD 128          // hidden dim (= H*C = D_IN)
#define NEG_SLOPE 0.2f
#define EPSV 1e-16f
#define TILE 8192       // edges per partition tile

typedef unsigned short ushort_t;
typedef __attribute__((ext_vector_type(8))) short bf16x8;
typedef __attribute__((ext_vector_type(8))) _Float16 f16x8;
typedef __attribute__((ext_vector_type(4))) float f32x4;

// split fp32 -> hi (truncated bf16) + lo (RNE bf16 of residual); err ~2^-16 rel
__device__ inline void bsplit(float x, ushort_t& hi, ushort_t& lo) {
    unsigned u = __float_as_uint(x);
    hi = (ushort_t)(u >> 16);
    float res = x - __uint_as_float(u & 0xffff0000u);
    unsigned v = __float_as_uint(res);
    lo = (ushort_t)((v + 0x7FFFu + ((v >> 16) & 1u)) >> 16);
}

// ---------------- fused: edge partition histogram + W split/swizzle ----------------
// blocks [0,NT): per-tile bucket histogram of dst>>8.
// blocks [NT,NT+64): layer-1 W bf16 hi/lo split; [NT+64,NT+128): layer-2 fp16.
__global__ __launch_bounds__(256) void pre_build(const int* __restrict__ dst,
                                                 int* __restrict__ tileHist, int E, int NT,
                                                 const float* __restrict__ W1,
                                                 const float* __restrict__ W2,
                                                 ushort_t* __restrict__ Whs1,
                                                 ushort_t* __restrict__ Wls1,
                                                 ushort_t* __restrict__ Whs2,
                                                 ushort_t* __restrict__ Wls2) {
    int t = threadIdx.x;
    if ((int)blockIdx.x < NT) {
        __shared__ int hist[256];
        hist[t] = 0;
        __syncthreads();
        int base = blockIdx.x * TILE;
        int end = base + TILE; if (end > E) end = E;
        for (int i = base + t; i < end; i += 256)
            atomicAdd(&hist[dst[i] >> 8], 1);
        __syncthreads();
        tileHist[blockIdx.x * 256 + t] = hist[t];
        return;
    }
    int blk = blockIdx.x - NT;           // 0..127
    bool layer2 = blk >= 64;
    int idx = (blk & 63) * 256 + t;      // 0..16383
    int j    = idx & 7;
    int lane = (idx >> 3) & 63;
    int ks   = (idx >> 9) & 3;
    int ct   = idx >> 11;
    int n = ct * 16 + (lane & 15);
    int k = ks * 32 + (lane >> 4) * 8 + j;
    if (!layer2) {
        ushort_t hi, lo;
        bsplit(W1[k * 128 + n], hi, lo);
        Whs1[idx] = hi;
        Wls1[idx] = lo;
    } else {
        float v = W2[k * 128 + n];
        __half h = __float2half(v);
        __half l = __float2half(v - __half2float(h));
        Whs2[idx] = __half_as_ushort(h);
        Wls2[idx] = __half_as_ushort(l);
    }
}

// per-bucket scan of tile histogram: one block per bucket (NT <= 256).
// tileHist[t*256+b] becomes the within-bucket exclusive offset of tile t.
__global__ __launch_bounds__(256) void bucket_scan(int* __restrict__ tileHist,
                                                   int* __restrict__ bucketTotal, int NT) {
    __shared__ int s[256];
    int t = threadIdx.x, b = blockIdx.x;
    int v = (t < NT) ? tileHist[t * 256 + b] : 0;
    s[t] = v;
    __syncthreads();
    for (int o = 1; o < 256; o <<= 1) {
        int u = (t >= o) ? s[t - o] : 0;
        __syncthreads();
        s[t] += u;
        __syncthreads();
    }
    int excl = (t == 0) ? 0 : s[t - 1];
    if (t < NT) tileHist[t * 256 + b] = excl;
    if (t == 255) bucketTotal[b] = s[255];
}

// exclusive scan of 256 bucket totals -> bucketBase[257] (single block)
__global__ __launch_bounds__(256) void bucket_base(const int* __restrict__ bucketTotal,
                                                   int* __restrict__ bucketBase) {
    __shared__ int s[256];
    int t = threadIdx.x;
    s[t] = bucketTotal[t];
    __syncthreads();
    for (int o = 1; o < 256; o <<= 1) {
        int u = (t >= o) ? s[t - o] : 0;
        __syncthreads();
        s[t] += u;
        __syncthreads();
    }
    bucketBase[t] = (t == 0) ? 0 : s[t - 1];
    if (t == 255) bucketBase[256] = s[255];
}

// packed entry: (src<<8) | (dst&255)
__global__ __launch_bounds__(256) void part_scatter(const int* __restrict__ src,
                                                    const int* __restrict__ dst,
                                                    const int* __restrict__ tileHist,
                                                    const int* __restrict__ bucketBase,
                                                    int* __restrict__ part, int E) {
    __shared__ int cur[256];
    int t = threadIdx.x;
    cur[t] = tileHist[blockIdx.x * 256 + t] + bucketBase[t];
    __syncthreads();
    int base = blockIdx.x * TILE;
    int end = base + TILE; if (end > E) end = E;
    for (int i = base + t; i < end; i += 256) {
        int d = dst[i], s = src[i];
        int p = atomicAdd(&cur[d >> 8], 1);
        part[p] = (s << 8) | (d & 255);
    }
}

// Fused CSR build: per-bucket histogram -> LDS scan -> indptr (closed form:
// indptr[d] = bucketBase[b] + in-bucket-prefix + d) -> LDS-cursor scatter.
__global__ __launch_bounds__(256) void csr_build(const int* __restrict__ part,
                                                 const int* __restrict__ bucketBase,
                                                 int* __restrict__ indptr,
                                                 int* __restrict__ csr, int N, int E) {
    __shared__ int hist[256];
    __shared__ int pfx[256];
    __shared__ int cur[256];
    int t = threadIdx.x;
    int b = blockIdx.x;
    hist[t] = 0;
    __syncthreads();
    int s0 = bucketBase[b], s1 = bucketBase[b + 1];
    for (int i = s0 + t; i < s1; i += 256)
        atomicAdd(&hist[part[i] & 255], 1);
    __syncthreads();
    pfx[t] = hist[t];
    __syncthreads();
    for (int o = 1; o < 256; o <<= 1) {
        int u = (t >= o) ? pfx[t - o] : 0;
        __syncthreads();
        pfx[t] += u;
        __syncthreads();
    }
    int excl = (t == 0) ? 0 : pfx[t - 1];
    int d = b * 256 + t;
    int ip = s0 + excl + d;            // edges before d + self-loops before d
    if (d < N) indptr[d] = ip;
    if (b == 0 && t == 0) indptr[N] = E + N;
    cur[t] = ip;
    __syncthreads();
    for (int i = s0 + t; i < s1; i += 256) {
        int e = part[i];
        int p = atomicAdd(&cur[e & 255], 1);
        csr[p] = e >> 8;
    }
    __syncthreads();
    if (d < N) csr[cur[t]] = d;        // self-loop fills the one remaining slot
}

// ---------------- layer-1 GEMM: split-bf16 MFMA + fused attention logits ----------------
__global__ __launch_bounds__(256) void gemm_mfma(const float* __restrict__ A,
                                                 const ushort_t* __restrict__ Whs,
                                                 const ushort_t* __restrict__ Wls,
                                                 const float* __restrict__ a_s,
                                                 const float* __restrict__ a_d,
                                                 __half* __restrict__ h16,
                                                 float* __restrict__ als,
                                                 float* __restrict__ ald, int N) {
    const int gw   = (blockIdx.x * 256 + threadIdx.x) >> 6;
    const int lane = threadIdx.x & 63;
    const int r0   = gw * 16;
    if (r0 >= N) return;
    const int m = lane & 15;
    const int q = lane >> 4;

    bf16x8 ah[4], al[4];
    {
        int row = r0 + m;
        if (row >= N) row = N - 1;      // safe clamp; stores are guarded
        const float* ap = A + (size_t)row * HD;
        #pragma unroll
        for (int ks = 0; ks < 4; ++ks) {
            float4 v0 = *(const float4*)(ap + ks * 32 + q * 8);
            float4 v1 = *(const float4*)(ap + ks * 32 + q * 8 + 4);
            float vv[8] = {v0.x, v0.y, v0.z, v0.w, v1.x, v1.y, v1.z, v1.w};
            #pragma unroll
            for (int j = 0; j < 8; ++j) {
                ushort_t hb, lb;
                bsplit(vv[j], hb, lb);
                ah[ks][j] = (short)hb;
                al[ks][j] = (short)lb;
            }
        }
    }

    float ps[4] = {0,0,0,0};
    float pd[4] = {0,0,0,0};

    #pragma unroll 1
    for (int ct = 0; ct < 8; ++ct) {
        f32x4 acc = {0.f, 0.f, 0.f, 0.f};
        #pragma unroll
        for (int ks = 0; ks < 4; ++ks) {
            bf16x8 wh = *(const bf16x8*)(Whs + ((size_t)(ct * 4 + ks) * 64 + lane) * 8);
            bf16x8 wl = *(const bf16x8*)(Wls + ((size_t)(ct * 4 + ks) * 64 + lane) * 8);
            acc = __builtin_amdgcn_mfma_f32_16x16x32_bf16(ah[ks], wh, acc, 0, 0, 0);
            acc = __builtin_amdgcn_mfma_f32_16x16x32_bf16(al[ks], wh, acc, 0, 0, 0);
            acc = __builtin_amdgcn_mfma_f32_16x16x32_bf16(ah[ks], wl, acc, 0, 0, 0);
        }
        const int col = ct * 16 + m;
        const float asv = a_s[col], adv = a_d[col];
        #pragma unroll
        for (int reg = 0; reg < 4; ++reg) {
            ps[reg] += acc[reg] * asv;
            pd[reg] += acc[reg] * adv;
            int row = r0 + q * 4 + reg;
            if (row < N) h16[(size_t)row * HD + col] = __float2half(acc[reg]);
        }
        if (ct == 3 || ct == 7) {          // head boundary: reduce over m-lanes
            int head = ct >> 2;
            #pragma unroll
            for (int reg = 0; reg < 4; ++reg) {
                float vs = ps[reg], vd = pd[reg];
                for (int o = 8; o >= 1; o >>= 1) {
                    vs += __shfl_xor(vs, o, 64);
                    vd += __shfl_xor(vd, o, 64);
                }
                if (m == 0) {
                    int row = r0 + q * 4 + reg;
                    if (row < N) { als[2 * row + head] = vs; ald[2 * row + head] = vd; }
                }
                ps[reg] = 0.f;  pd[reg] = 0.f;
            }
        }
    }
}

// ---------------- layer-2 GEMM: native f16 MFMA (A exact fp16, W 2-term) ----------------
__global__ __launch_bounds__(256) void gemm_mfma_f16(const __half* __restrict__ A,
                                                     const ushort_t* __restrict__ Whs,
                                                     const ushort_t* __restrict__ Wls,
                                                     const float* __restrict__ a_s,
                                                     const float* __restrict__ a_d,
                                                     __half* __restrict__ h16,
                                                     float* __restrict__ als,
                                                     float* __restrict__ ald, int N) {
    const int gw   = (blockIdx.x * 256 + threadIdx.x) >> 6;
    const int lane = threadIdx.x & 63;
    const int r0   = gw * 16;
    if (r0 >= N) return;
    const int m = lane & 15;
    const int q = lane >> 4;

    f16x8 ah[4];
    {
        int row = r0 + m;
        if (row >= N) row = N - 1;
        const __half* ap = A + (size_t)row * HD;
        #pragma unroll
        for (int ks = 0; ks < 4; ++ks)
            ah[ks] = *(const f16x8*)(ap + ks * 32 + q * 8);
    }

    float ps[4] = {0,0,0,0};
    float pd[4] = {0,0,0,0};

    #pragma unroll 1
    for (int ct = 0; ct < 8; ++ct) {
        f32x4 acc = {0.f, 0.f, 0.f, 0.f};
        #pragma unroll
        for (int ks = 0; ks < 4; ++ks) {
            f16x8 wh = *(const f16x8*)(Whs + ((size_t)(ct * 4 + ks) * 64 + lane) * 8);
            f16x8 wl = *(const f16x8*)(Wls + ((size_t)(ct * 4 + ks) * 64 + lane) * 8);
            acc = __builtin_amdgcn_mfma_f32_16x16x32_f16(ah[ks], wh, acc, 0, 0, 0);
            acc = __builtin_amdgcn_mfma_f32_16x16x32_f16(ah[ks], wl, acc, 0, 0, 0);
        }
        const int col = ct * 16 + m;
        const float asv = a_s[col], adv = a_d[col];
        #pragma unroll
        for (int reg = 0; reg < 4; ++reg) {
            ps[reg] += acc[reg] * asv;
            pd[reg] += acc[reg] * adv;
            int row = r0 + q * 4 + reg;
            if (row < N) h16[(size_t)row * HD + col] = __float2half(acc[reg]);
        }
        if (ct == 3 || ct == 7) {
            int head = ct >> 2;
            #pragma unroll
            for (int reg = 0; reg < 4; ++reg) {
                float vs = ps[reg], vd = pd[reg];
                for (int o = 8; o >= 1; o >>= 1) {
                    vs += __shfl_xor(vs, o, 64);
                    vd += __shfl_xor(vd, o, 64);
                }
                if (m == 0) {
                    int row = r0 + q * 4 + reg;
                    if (row < N) { als[2 * row + head] = vs; ald[2 * row + head] = vd; }
                }
                ps[reg] = 0.f;  pd[reg] = 0.f;
            }
        }
    }
}

// ---------------- GAT aggregation: one wave per dst node, DUAL-EDGE gather ----------------
// Lanes 0-31 process even edges, 32-63 odd edges; each lane covers 4 channels
// (half4 loads). 16 edges in flight per 8-unrolled burst. Combine via xor-32.
__global__ __launch_bounds__(256) void gat_aggregate(const __half* __restrict__ h,
                                                     const float* __restrict__ als,
                                                     const float* __restrict__ ald,
                                                     const int* __restrict__ indptr,
                                                     const int* __restrict__ csr,
                                                     const float* __restrict__ bias,
                                                     __half* __restrict__ out,
                                                     const float* __restrict__ Wh,
                                                     float* __restrict__ svec, int N) {
    __shared__ int2 ebuf[4][64];       // per-wave strip (wave-private, no barrier)
    int w    = (blockIdx.x * blockDim.x + threadIdx.x) >> 6;
    int lane = threadIdx.x & 63;
    int wv   = (threadIdx.x >> 6);
    if (w >= N) return;
    int start = indptr[w], end = indptr[w + 1];
    float ad0 = ald[2 * w], ad1 = ald[2 * w + 1];
    const int sl = lane & 31;          // channel group: channels sl*4 .. sl*4+3
    const int g  = lane >> 5;          // edge parity handled by this lane
    const int c0 = sl * 4;
    const bool headlo = (sl < 16);     // all 4 channels in head0 iff sl<16

    float a0 = 0.f, a1 = 0.f, a2 = 0.f, a3 = 0.f, dsum = 0.f;
    for (int base = start; base < end; base += 64) {
        int i = base + lane;
        int idx = i < end ? i : end - 1;
        int s = csr[idx];
        unsigned wpack = 0u;
        if (i < end) {
            float2 av = *(const float2*)&als[2 * s];
            float e0 = av.x + ad0;
            float e1 = av.y + ad1;
            e0 = e0 > 0.f ? e0 : NEG_SLOPE * e0;
            e1 = e1 > 0.f ? e1 : NEG_SLOPE * e1;
            __half p0 = __float2half(__expf(e0));
            __half p1 = __float2half(__expf(e1));
            wpack = ((unsigned)__half_as_ushort(p1) << 16) | __half_as_ushort(p0);
        }
        ebuf[wv][lane] = make_int2(s, (int)wpack);   // intra-wave RAW: lgkmcnt-ordered
        int nl = end - base; if (nl > 64) nl = 64;
        int nit = (nl + 15) >> 4;       // 16 edges per iteration
        for (int b = 0; b < nit; ++b) {
            int j = b * 16 + g;          // lane's edges: j, j+2, ..., j+14 (<= 63)
            int2 e[8];
            #pragma unroll
            for (int u = 0; u < 8; ++u) e[u] = ebuf[wv][j + 2 * u];
            float wa[8];
            #pragma unroll
            for (int u = 0; u < 8; ++u) {
                unsigned wp = (unsigned)e[u].y;      // zero weight beyond nl
                unsigned bits = headlo ? (wp & 0xffffu) : (wp >> 16);
                wa[u] = __half2float(__ushort_as_half((ushort_t)bits));
            }
            uint2 hv[8];
            #pragma unroll
            for (int u = 0; u < 8; ++u)
                hv[u] = *(const uint2*)&h[(size_t)e[u].x * HD + c0];
            #pragma unroll
            for (int u = 0; u < 8; ++u) {
                float2 f01 = __half22float2(*(__half2*)&hv[u].x);
                float2 f23 = __half22float2(*(__half2*)&hv[u].y);
                dsum += wa[u];
                a0 += wa[u] * f01.x;
                a1 += wa[u] * f01.y;
                a2 += wa[u] * f23.x;
                a3 += wa[u] * f23.y;
            }
        }
    }
    // combine the two edge parities (lane <-> lane^32 hold same channels)
    dsum += __shfl_xor(dsum, 32, 64);
    a0 += __shfl_xor(a0, 32, 64);
    a1 += __shfl_xor(a1, 32, 64);
    a2 += __shfl_xor(a2, 32, 64);
    a3 += __shfl_xor(a3, 32, 64);
    float D = dsum + EPSV;              // identical across lanes of a head
    float o0 = a0 / D + bias[c0 + 0];
    float o1 = a1 / D + bias[c0 + 1];
    float o2 = a2 / D + bias[c0 + 2];
    float o3 = a3 / D + bias[c0 + 3];
    o0 = o0 > 0.f ? o0 : 0.f;
    o1 = o1 > 0.f ? o1 : 0.f;
    o2 = o2 > 0.f ? o2 : 0.f;
    o3 = o3 > 0.f ? o3 : 0.f;

    if (svec) {
        const float4 wv4 = *(const float4*)&Wh[c0];
        float part = o0 * wv4.x + o1 * wv4.y + o2 * wv4.z + o3 * wv4.w;
        // channels fully covered by sl 0..31 (duplicated across g): reduce 32
        for (int o = 16; o >= 1; o >>= 1) part += __shfl_xor(part, o, 64);
        if (lane == 0) svec[w] = part;
    } else if (g == 0) {
        uint2 pack;
        *(__half2*)&pack.x = __halves2half2(__float2half(o0), __float2half(o1));
        *(__half2*)&pack.y = __halves2half2(__float2half(o2), __float2half(o3));
        *(uint2*)&out[(size_t)w * HD + c0] = pack;
    }
}

// ---------------- mean pool + head (inline graph-bound binary search) ----------------
__global__ __launch_bounds__(256) void pool_head(const float* __restrict__ s,
                                                 const int* __restrict__ batch,
                                                 const float* __restrict__ bh,
                                                 float* __restrict__ out, int N, int G) {
    __shared__ float partial[4];
    int g = blockIdx.x, t = threadIdx.x;
    auto lb = [&](int key) {
        int lo = 0, hi = N;
        while (lo < hi) {
            int mid = (lo + hi) >> 1;
            if (batch[mid] < key) lo = mid + 1; else hi = mid;
        }
        return lo;
    };
    int a = lb(g), b = lb(g + 1);
    float sum = 0.f;
    for (int i = a + t; i < b; i += 256) sum += s[i];
    for (int o = 32; o >= 1; o >>= 1) sum += __shfl_xor(sum, o, 64);
    if ((t & 63) == 0) partial[t >> 6] = sum;
    __syncthreads();
    if (t == 0) {
        float cnt = (float)(b - a); if (cnt < 1.f) cnt = 1.f;
        out[g] = (partial[0] + partial[1] + partial[2] + partial[3]) / cnt + bh[0];
    }
}

// ---------------- launch ----------------
extern "C" void kernel_launch(void* const* d_in, const int* in_sizes, int n_in,
                              void* d_out, int out_size, void* d_ws, size_t ws_size,
                              hipStream_t stream) {
    const float* x     = (const float*)d_in[0];
    const int*   ei    = (const int*)d_in[1];
    const int*   batch = (const int*)d_in[2];
    const float* W1  = (const float*)d_in[3];
    const float* as1 = (const float*)d_in[4];
    const float* ad1 = (const float*)d_in[5];
    const float* b1  = (const float*)d_in[6];
    const float* W2  = (const float*)d_in[7];
    const float* as2 = (const float*)d_in[8];
    const float* ad2 = (const float*)d_in[9];
    const float* b2  = (const float*)d_in[10];
    const float* Wh  = (const float*)d_in[11];
    const float* bh  = (const float*)d_in[12];
    float* out = (float*)d_out;

    const int N = in_sizes[0] / HD;
    const int E = in_sizes[1] / 2;
    const int G = out_size;
    const int* srcp = ei;
    const int* dstp = ei + E;
    const int NBK = (N + 255) / 256;      // coarse buckets (dst>>8)
    const int NT  = (E + TILE - 1) / TILE;

    char* ws = (char*)d_ws;
    size_t off = 0;
    auto alloc = [&](size_t bytes) -> void* {
        void* p = ws + off;
        off += (bytes + 255) & ~(size_t)255;
        return p;
    };
    __half* h16   = (__half*)alloc((size_t)N * HD * 2);
    __half* ob16  = (__half*)alloc((size_t)N * HD * 2);
    float* als    = (float*)alloc((size_t)N * 2 * 4);
    float* ald    = (float*)alloc((size_t)N * 2 * 4);
    float* svec   = (float*)alloc((size_t)N * 4);
    int*   indptr = (int*)  alloc((size_t)(N + 1) * 4);
    int*   csr    = (int*)  alloc((size_t)(E + N) * 4);
    int*   tileHist    = (int*)alloc((size_t)NT * 256 * 4);
    int*   bucketTotal = (int*)alloc(256 * 4);
    int*   bucketBase  = (int*)alloc(257 * 4);
    int*   part   = (int*)  alloc((size_t)E * 4);
    ushort_t* Whs1 = (ushort_t*)alloc(16384 * 2);
    ushort_t* Wls1 = (ushort_t*)alloc(16384 * 2);
    ushort_t* Whs2 = (ushort_t*)alloc(16384 * 2);
    ushort_t* Wls2 = (ushort_t*)alloc(16384 * 2);

    // CSR build: histogram (fused with W prep) -> parallel per-bucket tile scan
    // -> 256-scan -> bucketed scatter -> fused hist+scan+scatter per bucket
    pre_build<<<NT + 128, 256, 0, stream>>>(dstp, tileHist, E, NT,
                                            W1, W2, Whs1, Wls1, Whs2, Wls2);
    bucket_scan<<<256, 256, 0, stream>>>(tileHist, bucketTotal, NT);
    bucket_base<<<1, 256, 0, stream>>>(bucketTotal, bucketBase);
    part_scatter<<<NT, 256, 0, stream>>>(srcp, dstp, tileHist, bucketBase, part, E);
    csr_build<<<NBK, 256, 0, stream>>>(part, bucketBase, indptr, csr, N, E);

    const int nwaves  = (N + 15) / 16;
    const int gblocks = (nwaves + 3) / 4;
    int wgrid = (N * 64 + 255) / 256;

    // layer 1 (split-bf16 MFMA; logits fused; h stored fp16)
    gemm_mfma<<<gblocks, 256, 0, stream>>>(x, Whs1, Wls1, as1, ad1, h16, als, ald, N);
    gat_aggregate<<<wgrid, 256, 0, stream>>>(h16, als, ald, indptr, csr, b1, ob16,
                                             nullptr, nullptr, N);
    // layer 2 (native f16 MFMA: A exact fp16, W 2-term fp16 split)
    gemm_mfma_f16<<<gblocks, 256, 0, stream>>>(ob16, Whs2, Wls2, as2, ad2, h16,
                                               als, ald, N);
    gat_aggregate<<<wgrid, 256, 0, stream>>>(h16, als, ald, indptr, csr, b2, nullptr,
                                             Wh, svec, N);
    // pool + head (graph bounds via inline binary search)
    pool_head<<<G, 256, 0, stream>>>(svec, batch, bh, out, N, G);
}

// Round 14
// 246.782 us; speedup vs baseline: 1.0248x; 1.0248x over previous
//
#include <hip/hip_runtime.h>
#include <hip/hip_fp16.h>
#include <math.h>

#define HD 128          // hidden dim (= H*C = D_IN)
#define NEG_SLOPE 0.2f
#define EPSV 1e-16f
#define TILE 8192       // edges per partition tile

typedef unsigned short ushort_t;
typedef __attribute__((ext_vector_type(8))) short bf16x8;
typedef __attribute__((ext_vector_type(8))) _Float16 f16x8;
typedef __attribute__((ext_vector_type(4))) float f32x4;

// split fp32 -> hi (truncated bf16) + lo (RNE bf16 of residual); err ~2^-16 rel
__device__ inline void bsplit(float x, ushort_t& hi, ushort_t& lo) {
    unsigned u = __float_as_uint(x);
    hi = (ushort_t)(u >> 16);
    float res = x - __uint_as_float(u & 0xffff0000u);
    unsigned v = __float_as_uint(res);
    lo = (ushort_t)((v + 0x7FFFu + ((v >> 16) & 1u)) >> 16);
}

// ---------------- fused: edge partition histogram + W split/swizzle ----------------
// blocks [0,NT): per-tile bucket histogram of dst>>8.
// blocks [NT,NT+64): layer-1 W bf16 hi/lo split; [NT+64,NT+128): layer-2 fp16.
__global__ __launch_bounds__(256) void pre_build(const int* __restrict__ dst,
                                                 int* __restrict__ tileHist, int E, int NT,
                                                 const float* __restrict__ W1,
                                                 const float* __restrict__ W2,
                                                 ushort_t* __restrict__ Whs1,
                                                 ushort_t* __restrict__ Wls1,
                                                 ushort_t* __restrict__ Whs2,
                                                 ushort_t* __restrict__ Wls2) {
    int t = threadIdx.x;
    if ((int)blockIdx.x < NT) {
        __shared__ int hist[256];
        hist[t] = 0;
        __syncthreads();
        int base = blockIdx.x * TILE;
        int end = base + TILE; if (end > E) end = E;
        for (int i = base + t; i < end; i += 256)
            atomicAdd(&hist[dst[i] >> 8], 1);
        __syncthreads();
        tileHist[blockIdx.x * 256 + t] = hist[t];
        return;
    }
    int blk = blockIdx.x - NT;           // 0..127
    bool layer2 = blk >= 64;
    int idx = (blk & 63) * 256 + t;      // 0..16383
    int j    = idx & 7;
    int lane = (idx >> 3) & 63;
    int ks   = (idx >> 9) & 3;
    int ct   = idx >> 11;
    int n = ct * 16 + (lane & 15);
    int k = ks * 32 + (lane >> 4) * 8 + j;
    if (!layer2) {
        ushort_t hi, lo;
        bsplit(W1[k * 128 + n], hi, lo);
        Whs1[idx] = hi;
        Wls1[idx] = lo;
    } else {
        float v = W2[k * 128 + n];
        __half h = __float2half(v);
        __half l = __float2half(v - __half2float(h));
        Whs2[idx] = __half_as_ushort(h);
        Wls2[idx] = __half_as_ushort(l);
    }
}

// per-bucket scan of tile histogram: one block per bucket (NT <= 256).
__global__ __launch_bounds__(256) void bucket_scan(int* __restrict__ tileHist,
                                                   int* __restrict__ bucketTotal, int NT) {
    __shared__ int s[256];
    int t = threadIdx.x, b = blockIdx.x;
    int v = (t < NT) ? tileHist[t * 256 + b] : 0;
    s[t] = v;
    __syncthreads();
    for (int o = 1; o < 256; o <<= 1) {
        int u = (t >= o) ? s[t - o] : 0;
        __syncthreads();
        s[t] += u;
        __syncthreads();
    }
    int excl = (t == 0) ? 0 : s[t - 1];
    if (t < NT) tileHist[t * 256 + b] = excl;
    if (t == 255) bucketTotal[b] = s[255];
}

// exclusive scan of 256 bucket totals -> bucketBase[257] (single block)
__global__ __launch_bounds__(256) void bucket_base(const int* __restrict__ bucketTotal,
                                                   int* __restrict__ bucketBase) {
    __shared__ int s[256];
    int t = threadIdx.x;
    s[t] = bucketTotal[t];
    __syncthreads();
    for (int o = 1; o < 256; o <<= 1) {
        int u = (t >= o) ? s[t - o] : 0;
        __syncthreads();
        s[t] += u;
        __syncthreads();
    }
    bucketBase[t] = (t == 0) ? 0 : s[t - 1];
    if (t == 255) bucketBase[256] = s[255];
}

// packed entry: (src<<8) | (dst&255)
__global__ __launch_bounds__(256) void part_scatter(const int* __restrict__ src,
                                                    const int* __restrict__ dst,
                                                    const int* __restrict__ tileHist,
                                                    const int* __restrict__ bucketBase,
                                                    int* __restrict__ part, int E) {
    __shared__ int cur[256];
    int t = threadIdx.x;
    cur[t] = tileHist[blockIdx.x * 256 + t] + bucketBase[t];
    __syncthreads();
    int base = blockIdx.x * TILE;
    int end = base + TILE; if (end > E) end = E;
    for (int i = base + t; i < end; i += 256) {
        int d = dst[i], s = src[i];
        int p = atomicAdd(&cur[d >> 8], 1);
        part[p] = (s << 8) | (d & 255);
    }
}

// Fused CSR build: per-bucket histogram -> LDS scan -> indptr (closed form:
// indptr[d] = bucketBase[b] + in-bucket-prefix + d) -> LDS-cursor scatter.
__global__ __launch_bounds__(256) void csr_build(const int* __restrict__ part,
                                                 const int* __restrict__ bucketBase,
                                                 int* __restrict__ indptr,
                                                 int* __restrict__ csr, int N, int E) {
    __shared__ int hist[256];
    __shared__ int pfx[256];
    __shared__ int cur[256];
    int t = threadIdx.x;
    int b = blockIdx.x;
    hist[t] = 0;
    __syncthreads();
    int s0 = bucketBase[b], s1 = bucketBase[b + 1];
    for (int i = s0 + t; i < s1; i += 256)
        atomicAdd(&hist[part[i] & 255], 1);
    __syncthreads();
    pfx[t] = hist[t];
    __syncthreads();
    for (int o = 1; o < 256; o <<= 1) {
        int u = (t >= o) ? pfx[t - o] : 0;
        __syncthreads();
        pfx[t] += u;
        __syncthreads();
    }
    int excl = (t == 0) ? 0 : pfx[t - 1];
    int d = b * 256 + t;
    int ip = s0 + excl + d;            // edges before d + self-loops before d
    if (d < N) indptr[d] = ip;
    if (b == 0 && t == 0) indptr[N] = E + N;
    cur[t] = ip;
    __syncthreads();
    for (int i = s0 + t; i < s1; i += 256) {
        int e = part[i];
        int p = atomicAdd(&cur[e & 255], 1);
        csr[p] = e >> 8;
    }
    __syncthreads();
    if (d < N) csr[cur[t]] = d;        // self-loop fills the one remaining slot
}

// ---------------- layer-1 GEMM: split-bf16 MFMA + fused attention logits ----------------
__global__ __launch_bounds__(256) void gemm_mfma(const float* __restrict__ A,
                                                 const ushort_t* __restrict__ Whs,
                                                 const ushort_t* __restrict__ Wls,
                                                 const float* __restrict__ a_s,
                                                 const float* __restrict__ a_d,
                                                 __half* __restrict__ h16,
                                                 float* __restrict__ als,
                                                 float* __restrict__ ald, int N) {
    const int gw   = (blockIdx.x * 256 + threadIdx.x) >> 6;
    const int lane = threadIdx.x & 63;
    const int r0   = gw * 16;
    if (r0 >= N) return;
    const int m = lane & 15;
    const int q = lane >> 4;

    bf16x8 ah[4], al[4];
    {
        int row = r0 + m;
        if (row >= N) row = N - 1;      // safe clamp; stores are guarded
        const float* ap = A + (size_t)row * HD;
        #pragma unroll
        for (int ks = 0; ks < 4; ++ks) {
            float4 v0 = *(const float4*)(ap + ks * 32 + q * 8);
            float4 v1 = *(const float4*)(ap + ks * 32 + q * 8 + 4);
            float vv[8] = {v0.x, v0.y, v0.z, v0.w, v1.x, v1.y, v1.z, v1.w};
            #pragma unroll
            for (int j = 0; j < 8; ++j) {
                ushort_t hb, lb;
                bsplit(vv[j], hb, lb);
                ah[ks][j] = (short)hb;
                al[ks][j] = (short)lb;
            }
        }
    }

    float ps[4] = {0,0,0,0};
    float pd[4] = {0,0,0,0};

    #pragma unroll 1
    for (int ct = 0; ct < 8; ++ct) {
        f32x4 acc = {0.f, 0.f, 0.f, 0.f};
        #pragma unroll
        for (int ks = 0; ks < 4; ++ks) {
            bf16x8 wh = *(const bf16x8*)(Whs + ((size_t)(ct * 4 + ks) * 64 + lane) * 8);
            bf16x8 wl = *(const bf16x8*)(Wls + ((size_t)(ct * 4 + ks) * 64 + lane) * 8);
            acc = __builtin_amdgcn_mfma_f32_16x16x32_bf16(ah[ks], wh, acc, 0, 0, 0);
            acc = __builtin_amdgcn_mfma_f32_16x16x32_bf16(al[ks], wh, acc, 0, 0, 0);
            acc = __builtin_amdgcn_mfma_f32_16x16x32_bf16(ah[ks], wl, acc, 0, 0, 0);
        }
        const int col = ct * 16 + m;
        const float asv = a_s[col], adv = a_d[col];
        #pragma unroll
        for (int reg = 0; reg < 4; ++reg) {
            ps[reg] += acc[reg] * asv;
            pd[reg] += acc[reg] * adv;
            int row = r0 + q * 4 + reg;
            if (row < N) h16[(size_t)row * HD + col] = __float2half(acc[reg]);
        }
        if (ct == 3 || ct == 7) {          // head boundary: reduce over m-lanes
            int head = ct >> 2;
            #pragma unroll
            for (int reg = 0; reg < 4; ++reg) {
                float vs = ps[reg], vd = pd[reg];
                for (int o = 8; o >= 1; o >>= 1) {
                    vs += __shfl_xor(vs, o, 64);
                    vd += __shfl_xor(vd, o, 64);
                }
                if (m == 0) {
                    int row = r0 + q * 4 + reg;
                    if (row < N) { als[2 * row + head] = vs; ald[2 * row + head] = vd; }
                }
                ps[reg] = 0.f;  pd[reg] = 0.f;
            }
        }
    }
}

// ---------------- layer-2 GEMM: native f16 MFMA (A exact fp16, W 2-term) ----------------
__global__ __launch_bounds__(256) void gemm_mfma_f16(const __half* __restrict__ A,
                                                     const ushort_t* __restrict__ Whs,
                                                     const ushort_t* __restrict__ Wls,
                                                     const float* __restrict__ a_s,
                                                     const float* __restrict__ a_d,
                                                     __half* __restrict__ h16,
                                                     float* __restrict__ als,
                                                     float* __restrict__ ald, int N) {
    const int gw   = (blockIdx.x * 256 + threadIdx.x) >> 6;
    const int lane = threadIdx.x & 63;
    const int r0   = gw * 16;
    if (r0 >= N) return;
    const int m = lane & 15;
    const int q = lane >> 4;

    f16x8 ah[4];
    {
        int row = r0 + m;
        if (row >= N) row = N - 1;
        const __half* ap = A + (size_t)row * HD;
        #pragma unroll
        for (int ks = 0; ks < 4; ++ks)
            ah[ks] = *(const f16x8*)(ap + ks * 32 + q * 8);
    }

    float ps[4] = {0,0,0,0};
    float pd[4] = {0,0,0,0};

    #pragma unroll 1
    for (int ct = 0; ct < 8; ++ct) {
        f32x4 acc = {0.f, 0.f, 0.f, 0.f};
        #pragma unroll
        for (int ks = 0; ks < 4; ++ks) {
            f16x8 wh = *(const f16x8*)(Whs + ((size_t)(ct * 4 + ks) * 64 + lane) * 8);
            f16x8 wl = *(const f16x8*)(Wls + ((size_t)(ct * 4 + ks) * 64 + lane) * 8);
            acc = __builtin_amdgcn_mfma_f32_16x16x32_f16(ah[ks], wh, acc, 0, 0, 0);
            acc = __builtin_amdgcn_mfma_f32_16x16x32_f16(ah[ks], wl, acc, 0, 0, 0);
        }
        const int col = ct * 16 + m;
        const float asv = a_s[col], adv = a_d[col];
        #pragma unroll
        for (int reg = 0; reg < 4; ++reg) {
            ps[reg] += acc[reg] * asv;
            pd[reg] += acc[reg] * adv;
            int row = r0 + q * 4 + reg;
            if (row < N) h16[(size_t)row * HD + col] = __float2half(acc[reg]);
        }
        if (ct == 3 || ct == 7) {
            int head = ct >> 2;
            #pragma unroll
            for (int reg = 0; reg < 4; ++reg) {
                float vs = ps[reg], vd = pd[reg];
                for (int o = 8; o >= 1; o >>= 1) {
                    vs += __shfl_xor(vs, o, 64);
                    vd += __shfl_xor(vd, o, 64);
                }
                if (m == 0) {
                    int row = r0 + q * 4 + reg;
                    if (row < N) { als[2 * row + head] = vs; ald[2 * row + head] = vd; }
                }
                ps[reg] = 0.f;  pd[reg] = 0.f;
            }
        }
    }
}

// ---------------- GAT aggregation: one wave per dst node ----------------
// LDS strip broadcast + fused denominator (round-12 best form): 1 ds_write_b64
// per 64 edges, 1 broadcast ds_read_b64 per edge, per-lane exact denominator.
__global__ __launch_bounds__(256) void gat_aggregate(const __half* __restrict__ h,
                                                     const float* __restrict__ als,
                                                     const float* __restrict__ ald,
                                                     const int* __restrict__ indptr,
                                                     const int* __restrict__ csr,
                                                     const float* __restrict__ bias,
                                                     __half* __restrict__ out,
                                                     const float* __restrict__ Wh,
                                                     float* __restrict__ svec, int N) {
    __shared__ int2 ebuf[4][64];       // per-wave strip (wave-private, no barrier)
    int w    = (blockIdx.x * blockDim.x + threadIdx.x) >> 6;
    int lane = threadIdx.x & 63;
    int wv   = (threadIdx.x >> 6);
    if (w >= N) return;
    int start = indptr[w], end = indptr[w + 1];
    float ad0 = ald[2 * w], ad1 = ald[2 * w + 1];
    const bool head0 = (lane < 32);
    const int cbase = lane * 2;

    float accx = 0.f, accy = 0.f, dsum = 0.f;
    for (int base = start; base < end; base += 64) {
        int i = base + lane;
        int idx = i < end ? i : end - 1;
        int s = csr[idx];
        unsigned wpack = 0u;
        if (i < end) {
            float2 av = *(const float2*)&als[2 * s];
            float e0 = av.x + ad0;
            float e1 = av.y + ad1;
            e0 = e0 > 0.f ? e0 : NEG_SLOPE * e0;
            e1 = e1 > 0.f ? e1 : NEG_SLOPE * e1;
            __half p0 = __float2half(__expf(e0));
            __half p1 = __float2half(__expf(e1));
            wpack = ((unsigned)__half_as_ushort(p1) << 16) | __half_as_ushort(p0);
        }
        ebuf[wv][lane] = make_int2(s, (int)wpack);   // intra-wave RAW: lgkmcnt-ordered
        int nl = end - base; if (nl > 64) nl = 64;
        int nb = (nl + 7) >> 3;
        for (int b = 0; b < nb; ++b) {
            int j = b * 8;
            int2 e[8];
            #pragma unroll
            for (int u = 0; u < 8; ++u) e[u] = ebuf[wv][j + u];   // broadcast reads
            float wa[8];
            #pragma unroll
            for (int u = 0; u < 8; ++u) {
                unsigned wp = (unsigned)e[u].y;
                unsigned bits = head0 ? (wp & 0xffffu) : (wp >> 16);
                wa[u] = __half2float(__ushort_as_half((ushort_t)bits));
            }
            __half2 hv[8];
            #pragma unroll
            for (int u = 0; u < 8; ++u)
                hv[u] = *(const __half2*)&h[(size_t)e[u].x * HD + cbase];
            #pragma unroll
            for (int u = 0; u < 8; ++u) {
                float2 f = __half22float2(hv[u]);
                dsum += wa[u];
                accx += wa[u] * f.x;
                accy += wa[u] * f.y;
            }
        }
    }
    float D = dsum + EPSV;              // identical across lanes of a head
    float ox = accx / D + bias[cbase];
    float oy = accy / D + bias[cbase + 1];
    ox = ox > 0.f ? ox : 0.f;   // ReLU
    oy = oy > 0.f ? oy : 0.f;

    if (svec) {
        float2 wv2 = *(const float2*)&Wh[cbase];
        float part = ox * wv2.x + oy * wv2.y;
        for (int o = 32; o >= 1; o >>= 1) part += __shfl_xor(part, o, 64);
        if (lane == 0) svec[w] = part;
    } else {
        *(__half2*)&out[(size_t)w * HD + cbase] =
            __halves2half2(__float2half(ox), __float2half(oy));
    }
}

// ---------------- mean pool + head (inline graph-bound binary search) ----------------
__global__ __launch_bounds__(256) void pool_head(const float* __restrict__ s,
                                                 const int* __restrict__ batch,
                                                 const float* __restrict__ bh,
                                                 float* __restrict__ out, int N, int G) {
    __shared__ float partial[4];
    int g = blockIdx.x, t = threadIdx.x;
    auto lb = [&](int key) {
        int lo = 0, hi = N;
        while (lo < hi) {
            int mid = (lo + hi) >> 1;
            if (batch[mid] < key) lo = mid + 1; else hi = mid;
        }
        return lo;
    };
    int a = lb(g), b = lb(g + 1);
    float sum = 0.f;
    for (int i = a + t; i < b; i += 256) sum += s[i];
    for (int o = 32; o >= 1; o >>= 1) sum += __shfl_xor(sum, o, 64);
    if ((t & 63) == 0) partial[t >> 6] = sum;
    __syncthreads();
    if (t == 0) {
        float cnt = (float)(b - a); if (cnt < 1.f) cnt = 1.f;
        out[g] = (partial[0] + partial[1] + partial[2] + partial[3]) / cnt + bh[0];
    }
}

// ---------------- launch ----------------
extern "C" void kernel_launch(void* const* d_in, const int* in_sizes, int n_in,
                              void* d_out, int out_size, void* d_ws, size_t ws_size,
                              hipStream_t stream) {
    const float* x     = (const float*)d_in[0];
    const int*   ei    = (const int*)d_in[1];
    const int*   batch = (const int*)d_in[2];
    const float* W1  = (const float*)d_in[3];
    const float* as1 = (const float*)d_in[4];
    const float* ad1 = (const float*)d_in[5];
    const float* b1  = (const float*)d_in[6];
    const float* W2  = (const float*)d_in[7];
    const float* as2 = (const float*)d_in[8];
    const float* ad2 = (const float*)d_in[9];
    const float* b2  = (const float*)d_in[10];
    const float* Wh  = (const float*)d_in[11];
    const float* bh  = (const float*)d_in[12];
    float* out = (float*)d_out;

    const int N = in_sizes[0] / HD;
    const int E = in_sizes[1] / 2;
    const int G = out_size;
    const int* srcp = ei;
    const int* dstp = ei + E;
    const int NBK = (N + 255) / 256;      // coarse buckets (dst>>8)
    const int NT  = (E + TILE - 1) / TILE;

    char* ws = (char*)d_ws;
    size_t off = 0;
    auto alloc = [&](size_t bytes) -> void* {
        void* p = ws + off;
        off += (bytes + 255) & ~(size_t)255;
        return p;
    };
    __half* h16   = (__half*)alloc((size_t)N * HD * 2);
    __half* ob16  = (__half*)alloc((size_t)N * HD * 2);
    float* als    = (float*)alloc((size_t)N * 2 * 4);
    float* ald    = (float*)alloc((size_t)N * 2 * 4);
    float* svec   = (float*)alloc((size_t)N * 4);
    int*   indptr = (int*)  alloc((size_t)(N + 1) * 4);
    int*   csr    = (int*)  alloc((size_t)(E + N) * 4);
    int*   tileHist    = (int*)alloc((size_t)NT * 256 * 4);
    int*   bucketTotal = (int*)alloc(256 * 4);
    int*   bucketBase  = (int*)alloc(257 * 4);
    int*   part   = (int*)  alloc((size_t)E * 4);
    ushort_t* Whs1 = (ushort_t*)alloc(16384 * 2);
    ushort_t* Wls1 = (ushort_t*)alloc(16384 * 2);
    ushort_t* Whs2 = (ushort_t*)alloc(16384 * 2);
    ushort_t* Wls2 = (ushort_t*)alloc(16384 * 2);

    // CSR build: histogram (fused with W prep) -> parallel per-bucket tile scan
    // -> 256-scan -> bucketed scatter -> fused hist+scan+scatter per bucket
    pre_build<<<NT + 128, 256, 0, stream>>>(dstp, tileHist, E, NT,
                                            W1, W2, Whs1, Wls1, Whs2, Wls2);
    bucket_scan<<<256, 256, 0, stream>>>(tileHist, bucketTotal, NT);
    bucket_base<<<1, 256, 0, stream>>>(bucketTotal, bucketBase);
    part_scatter<<<NT, 256, 0, stream>>>(srcp, dstp, tileHist, bucketBase, part, E);
    csr_build<<<NBK, 256, 0, stream>>>(part, bucketBase, indptr, csr, N, E);

    const int nwaves  = (N + 15) / 16;
    const int gblocks = (nwaves + 3) / 4;
    int wgrid = (N * 64 + 255) / 256;

    // layer 1 (split-bf16 MFMA; logits fused; h stored fp16)
    gemm_mfma<<<gblocks, 256, 0, stream>>>(x, Whs1, Wls1, as1, ad1, h16, als, ald, N);
    gat_aggregate<<<wgrid, 256, 0, stream>>>(h16, als, ald, indptr, csr, b1, ob16,
                                             nullptr, nullptr, N);
    // layer 2 (native f16 MFMA: A exact fp16, W 2-term fp16 split)
    gemm_mfma_f16<<<gblocks, 256, 0, stream>>>(ob16, Whs2, Wls2, as2, ad2, h16,
                                               als, ald, N);
    gat_aggregate<<<wgrid, 256, 0, stream>>>(h16, als, ald, indptr, csr, b2, nullptr,
                                             Wh, svec, N);
    // pool + head (graph bounds via inline binary search)
    pool_head<<<G, 256, 0, stream>>>(svec, batch, bh, out, N, G);
}